// Round 10
// baseline (75.828 us; speedup 1.0000x reference)
//
#include <hip/hip_runtime.h>
#include <math.h>

#define BATCH 16384
#define N0 57
#define NX 3249          // 57*57
#define HS 5
#define NCLS 17
#define NTRI 15
#define EPSV 1e-4f
#define MPB 16           // matrices per block (grid 1024)

// ---------------------------------------------------------------- helpers
template<int CTRL>
__device__ __forceinline__ float dpp_mov0(float x) {
    return __int_as_float(__builtin_amdgcn_update_dpp(
        0, __float_as_int(x), CTRL, 0xF, 0xF, true));
}
// full 64-lane sum, result valid in lane 63, pure VALU (no LDS pipe)
__device__ __forceinline__ float wave_sum64(float x) {
    x += dpp_mov0<0x111>(x);   // row_shr:1
    x += dpp_mov0<0x112>(x);   // row_shr:2
    x += dpp_mov0<0x114>(x);   // row_shr:4
    x += dpp_mov0<0x118>(x);   // row_shr:8
    x += dpp_mov0<0x142>(x);   // row_bcast:15
    x += dpp_mov0<0x143>(x);   // row_bcast:31 -> lane 63 = total
    return x;
}

__device__ __forceinline__ float frcp(float x)  { return __builtin_amdgcn_rcpf(x); }
__device__ __forceinline__ float frsq(float x)  { return __builtin_amdgcn_rsqf(x); }
__device__ __forceinline__ float fsqrt(float x) { return __builtin_amdgcn_sqrtf(x); }

// ----------------------------------------------------------------- k_main
// Fused setup + bilinear. Per block: compute wc = W1@W2@W3 into LDS (cheap,
// amortized over 16 matrices), then stream 16 matrices (4 per wave x 4 iters).
// Column scheme (x symmetric): lane a owns column a, coalesced 64-dword reads;
// wc inner-loop reads are wave-uniform LDS broadcasts (== s_load perf, R3).
__global__ __launch_bounds__(256) void k_main(const float* __restrict__ x,
                                              const float* __restrict__ W1,
                                              const float* __restrict__ W2,
                                              const float* __restrict__ W3,
                                              float* __restrict__ y_out) {
    __shared__ float w23[100];        // W2@W3 (20x5)
    __shared__ float wcs[N0 * 8];     // wc rows padded to 8
    const int tid  = threadIdx.x;
    const int lane = tid & 63;
    const int wave = tid >> 6;

    // wc = W1@W2@W3 (redundant per block; ~400 cyc, amortized over 16 mats)
    if (tid < 100) {
        int k = tid / 5, j = tid % 5;
        float acc = 0.f;
        #pragma unroll
        for (int l = 0; l < 10; ++l) acc = fmaf(W2[k * 10 + l], W3[l * 5 + j], acc);
        w23[tid] = acc;
    }
    __syncthreads();
    if (tid < N0) {
        #pragma unroll
        for (int j = 0; j < 5; ++j) {
            float acc = 0.f;
            #pragma unroll
            for (int k = 0; k < 20; ++k) acc = fmaf(W1[tid * 20 + k], w23[k * 5 + j], acc);
            wcs[tid * 8 + j] = acc;
        }
    }
    __syncthreads();

    // per-lane Wc row (left operand of the outer product); one-time reads
    float wv[HS];
    {
        int a = (lane < N0) ? lane : 0;
        #pragma unroll
        for (int i = 0; i < HS; ++i) wv[i] = wcs[a * 8 + i];
        if (lane >= N0) { wv[0] = wv[1] = wv[2] = wv[3] = wv[4] = 0.f; }
    }

    const int lc = (lane < N0) ? lane : 56;          // clamp keeps loads in-bounds
    for (int it = 0; it < MPB / 4; ++it) {
        const int m = blockIdx.x * MPB + it * 4 + wave;
        const float* base = x + (size_t)m * NX + lc;

        float s[HS] = {0.f, 0.f, 0.f, 0.f, 0.f};
        #pragma unroll
        for (int b = 0; b < N0; ++b) {
            float xv = base[b * N0];                 // 64 consecutive dwords/wave
            #pragma unroll
            for (int j = 0; j < HS; ++j) s[j] = fmaf(xv, wcs[b * 8 + j], s[j]);
        }

        // upper-tri outer product + DPP reduction (VALU only)
        float p[NTRI];
        int u = 0;
        #pragma unroll
        for (int i = 0; i < HS; ++i)
            #pragma unroll
            for (int j = i; j < HS; ++j) { p[u] = wave_sum64(wv[i] * s[j]); ++u; }

        if (lane == 63) {
            float4* o = (float4*)&y_out[(size_t)m * 16];
            o[0] = make_float4(p[0],  p[1],  p[2],  p[3]);
            o[1] = make_float4(p[4],  p[5],  p[6],  p[7]);
            o[2] = make_float4(p[8],  p[9],  p[10], p[11]);
            o[3] = make_float4(p[12], p[13], p[14], 0.f);
        }
    }
}

// ------------------------------------------------------------------ k_eig
// One thread per matrix, SIMT-packed (64 matrices/wave). 5 cyclic sweeps
// (quadratic convergence; margin vs threshold is 5x). Fast-math natives;
// lin_w/lin_b via s_load (uniform indices).
__global__ __launch_bounds__(64) void k_eig(const float* __restrict__ y_in,
                                            const float* __restrict__ lin_w,
                                            const float* __restrict__ lin_b,
                                            float* __restrict__ out) {
    int m = blockIdx.x * 64 + threadIdx.x;
    const float4* yin = (const float4*)&y_in[(size_t)m * 16];
    float4 q0 = yin[0], q1 = yin[1], q2 = yin[2], q3 = yin[3];
    float tri[16] = {q0.x, q0.y, q0.z, q0.w, q1.x, q1.y, q1.z, q1.w,
                     q2.x, q2.y, q2.z, q2.w, q3.x, q3.y, q3.z, q3.w};

    float A[HS][HS], V[HS][HS];
    int t = 0;
    #pragma unroll
    for (int i = 0; i < HS; ++i)
        #pragma unroll
        for (int j = i; j < HS; ++j) { A[i][j] = tri[t]; A[j][i] = tri[t]; ++t; }
    #pragma unroll
    for (int i = 0; i < HS; ++i)
        #pragma unroll
        for (int j = 0; j < HS; ++j) V[i][j] = (i == j) ? 1.f : 0.f;

    #pragma unroll
    for (int sweep = 0; sweep < 5; ++sweep) {
        #pragma unroll
        for (int p = 0; p < HS - 1; ++p) {
            #pragma unroll
            for (int q = p + 1; q < HS; ++q) {
                float apq = A[p][q];
                float app = A[p][p], aqq = A[q][q];
                bool nz = fabsf(apq) > 1e-30f;
                float theta = (aqq - app) * 0.5f * frcp(apq);
                float tt = frcp(fabsf(theta) + fsqrt(fmaf(theta, theta, 1.f)));
                tt = copysignf(tt, theta);
                tt = nz ? tt : 0.f;
                float c = frsq(fmaf(tt, tt, 1.f));
                float sn = tt * c;
                #pragma unroll
                for (int k = 0; k < HS; ++k) {
                    float akp = A[k][p], akq = A[k][q];
                    A[k][p] = fmaf(c, akp, -sn * akq);
                    A[k][q] = fmaf(sn, akp,  c * akq);
                }
                #pragma unroll
                for (int k = 0; k < HS; ++k) {
                    float apk = A[p][k], aqk = A[q][k];
                    A[p][k] = fmaf(c, apk, -sn * aqk);
                    A[q][k] = fmaf(sn, apk,  c * aqk);
                }
                #pragma unroll
                for (int k = 0; k < HS; ++k) {
                    float vkp = V[k][p], vkq = V[k][q];
                    V[k][p] = fmaf(c, vkp, -sn * vkq);
                    V[k][q] = fmaf(sn, vkp,  c * vkq);
                }
            }
        }
    }

    float lwv[HS];
    #pragma unroll
    for (int i = 0; i < HS; ++i)
        lwv[i] = 0.69314718056f * __log2f(fmaxf(A[i][i], EPSV));

    float tri2[NTRI];
    t = 0;
    #pragma unroll
    for (int i = 0; i < HS; ++i) {
        float vi[HS];
        #pragma unroll
        for (int k = 0; k < HS; ++k) vi[k] = V[i][k] * lwv[k];
        #pragma unroll
        for (int j = i; j < HS; ++j) {
            float acc = 0.f;
            #pragma unroll
            for (int k = 0; k < HS; ++k) acc = fmaf(vi[k], V[j][k], acc);
            tri2[t++] = acc;
        }
    }

    #pragma unroll
    for (int c = 0; c < NCLS; ++c) {
        float acc = lin_b[c];
        #pragma unroll
        for (int k = 0; k < NTRI; ++k) acc = fmaf(tri2[k], lin_w[c * NTRI + k], acc);
        out[(size_t)m * NCLS + c] = acc;
    }
}

// ----------------------------------------------------------------- launch
extern "C" void kernel_launch(void* const* d_in, const int* in_sizes, int n_in,
                              void* d_out, int out_size, void* d_ws, size_t ws_size,
                              hipStream_t stream) {
    const float* x     = (const float*)d_in[0];
    const float* W1    = (const float*)d_in[1];
    const float* W2    = (const float*)d_in[2];
    const float* W3    = (const float*)d_in[3];
    const float* lin_w = (const float*)d_in[4];
    const float* lin_b = (const float*)d_in[5];
    float* out = (float*)d_out;
    float* y   = (float*)d_ws;     // 16384*16 floats

    k_main<<<BATCH / MPB, 256, 0, stream>>>(x, W1, W2, W3, y);
    k_eig<<<BATCH / 64, 64, 0, stream>>>(y, lin_w, lin_b, out);
}

// Round 11
// 48.145 us; speedup vs baseline: 1.5750x; 1.5750x over previous
//
#include <hip/hip_runtime.h>
#include <math.h>

#define BATCH 16384
#define N0 57
#define NX 3249          // 57*57
#define HS 5
#define NCLS 17
#define NTRI 15
#define EPSV 1e-4f

// ---------------------------------------------------------------- helpers
template<int CTRL>
__device__ __forceinline__ float dpp_mov0(float x) {
    return __int_as_float(__builtin_amdgcn_update_dpp(
        0, __float_as_int(x), CTRL, 0xF, 0xF, true));
}
// full 64-lane sum, result valid in lane 63, pure VALU (no LDS pipe)
__device__ __forceinline__ float wave_sum64(float x) {
    x += dpp_mov0<0x111>(x);   // row_shr:1
    x += dpp_mov0<0x112>(x);   // row_shr:2
    x += dpp_mov0<0x114>(x);   // row_shr:4
    x += dpp_mov0<0x118>(x);   // row_shr:8
    x += dpp_mov0<0x142>(x);   // row_bcast:15
    x += dpp_mov0<0x143>(x);   // row_bcast:31 -> lane 63 = total
    return x;
}

__device__ __forceinline__ float frcp(float x)  { return __builtin_amdgcn_rcpf(x); }
__device__ __forceinline__ float frsq(float x)  { return __builtin_amdgcn_rsqf(x); }
__device__ __forceinline__ float fsqrt(float x) { return __builtin_amdgcn_sqrtf(x); }

// ----------------------------------------------------------------- k_main
// R9's proven streaming structure (1 matrix per wave, grid 4096, no loop)
// + per-block wc = W1@W2@W3 preamble into LDS (removes k_setup dispatch).
// Column scheme (x symmetric): lane a owns column a, coalesced 64-dword
// reads; wc inner reads are wave-uniform LDS broadcasts (== s_load, R3).
__global__ __launch_bounds__(256) void k_main(const float* __restrict__ x,
                                              const float* __restrict__ W1,
                                              const float* __restrict__ W2,
                                              const float* __restrict__ W3,
                                              float* __restrict__ y_out) {
    __shared__ float w23[100];        // W2@W3 (20x5)
    __shared__ float wcs[N0 * 8];     // wc rows padded to 8
    const int tid  = threadIdx.x;
    const int lane = tid & 63;
    const int wave = tid >> 6;
    const int m    = blockIdx.x * 4 + wave;

    // ---- preamble: wc into LDS (~600 cyc, amortized/overlapped)
    if (tid < 100) {
        int k = tid / 5, j = tid % 5;
        float acc = 0.f;
        #pragma unroll
        for (int l = 0; l < 10; ++l) acc = fmaf(W2[k * 10 + l], W3[l * 5 + j], acc);
        w23[tid] = acc;
    }
    __syncthreads();
    if (tid < N0) {
        #pragma unroll
        for (int j = 0; j < 5; ++j) {
            float acc = 0.f;
            #pragma unroll
            for (int k = 0; k < 20; ++k) acc = fmaf(W1[tid * 20 + k], w23[k * 5 + j], acc);
            wcs[tid * 8 + j] = acc;
        }
    }
    __syncthreads();

    // per-lane Wc row (left operand of the outer product)
    float wv[HS];
    {
        int a = (lane < N0) ? lane : 0;
        #pragma unroll
        for (int i = 0; i < HS; ++i) wv[i] = wcs[a * 8 + i];
        if (lane >= N0) { wv[0] = wv[1] = wv[2] = wv[3] = wv[4] = 0.f; }
    }

    // ---- stream one matrix per wave: 57 coalesced 64-dword reads
    const int lc = (lane < N0) ? lane : 56;          // clamp keeps loads in-bounds
    const float* base = x + (size_t)m * NX + lc;
    float s[HS] = {0.f, 0.f, 0.f, 0.f, 0.f};
    #pragma unroll
    for (int b = 0; b < N0; ++b) {
        float xv = base[b * N0];
        #pragma unroll
        for (int j = 0; j < HS; ++j) s[j] = fmaf(xv, wcs[b * 8 + j], s[j]);
    }

    // upper-tri outer product + DPP reduction (VALU only)
    float p[NTRI];
    int u = 0;
    #pragma unroll
    for (int i = 0; i < HS; ++i)
        #pragma unroll
        for (int j = i; j < HS; ++j) { p[u] = wave_sum64(wv[i] * s[j]); ++u; }

    if (lane == 63) {
        float4* o = (float4*)&y_out[(size_t)m * 16];
        o[0] = make_float4(p[0],  p[1],  p[2],  p[3]);
        o[1] = make_float4(p[4],  p[5],  p[6],  p[7]);
        o[2] = make_float4(p[8],  p[9],  p[10], p[11]);
        o[3] = make_float4(p[12], p[13], p[14], 0.f);
    }
}

// ------------------------------------------------------------------ k_eig
// One thread per matrix, SIMT-packed (64 matrices/wave). 5 cyclic sweeps
// (R10-validated: absmax unchanged). Fast-math natives; lin_w/lin_b s_load.
__global__ __launch_bounds__(64) void k_eig(const float* __restrict__ y_in,
                                            const float* __restrict__ lin_w,
                                            const float* __restrict__ lin_b,
                                            float* __restrict__ out) {
    int m = blockIdx.x * 64 + threadIdx.x;
    const float4* yin = (const float4*)&y_in[(size_t)m * 16];
    float4 q0 = yin[0], q1 = yin[1], q2 = yin[2], q3 = yin[3];
    float tri[16] = {q0.x, q0.y, q0.z, q0.w, q1.x, q1.y, q1.z, q1.w,
                     q2.x, q2.y, q2.z, q2.w, q3.x, q3.y, q3.z, q3.w};

    float A[HS][HS], V[HS][HS];
    int t = 0;
    #pragma unroll
    for (int i = 0; i < HS; ++i)
        #pragma unroll
        for (int j = i; j < HS; ++j) { A[i][j] = tri[t]; A[j][i] = tri[t]; ++t; }
    #pragma unroll
    for (int i = 0; i < HS; ++i)
        #pragma unroll
        for (int j = 0; j < HS; ++j) V[i][j] = (i == j) ? 1.f : 0.f;

    #pragma unroll
    for (int sweep = 0; sweep < 5; ++sweep) {
        #pragma unroll
        for (int p = 0; p < HS - 1; ++p) {
            #pragma unroll
            for (int q = p + 1; q < HS; ++q) {
                float apq = A[p][q];
                float app = A[p][p], aqq = A[q][q];
                bool nz = fabsf(apq) > 1e-30f;
                float theta = (aqq - app) * 0.5f * frcp(apq);
                float tt = frcp(fabsf(theta) + fsqrt(fmaf(theta, theta, 1.f)));
                tt = copysignf(tt, theta);
                tt = nz ? tt : 0.f;
                float c = frsq(fmaf(tt, tt, 1.f));
                float sn = tt * c;
                #pragma unroll
                for (int k = 0; k < HS; ++k) {
                    float akp = A[k][p], akq = A[k][q];
                    A[k][p] = fmaf(c, akp, -sn * akq);
                    A[k][q] = fmaf(sn, akp,  c * akq);
                }
                #pragma unroll
                for (int k = 0; k < HS; ++k) {
                    float apk = A[p][k], aqk = A[q][k];
                    A[p][k] = fmaf(c, apk, -sn * aqk);
                    A[q][k] = fmaf(sn, apk,  c * aqk);
                }
                #pragma unroll
                for (int k = 0; k < HS; ++k) {
                    float vkp = V[k][p], vkq = V[k][q];
                    V[k][p] = fmaf(c, vkp, -sn * vkq);
                    V[k][q] = fmaf(sn, vkp,  c * vkq);
                }
            }
        }
    }

    float lwv[HS];
    #pragma unroll
    for (int i = 0; i < HS; ++i)
        lwv[i] = 0.69314718056f * __log2f(fmaxf(A[i][i], EPSV));

    float tri2[NTRI];
    t = 0;
    #pragma unroll
    for (int i = 0; i < HS; ++i) {
        float vi[HS];
        #pragma unroll
        for (int k = 0; k < HS; ++k) vi[k] = V[i][k] * lwv[k];
        #pragma unroll
        for (int j = i; j < HS; ++j) {
            float acc = 0.f;
            #pragma unroll
            for (int k = 0; k < HS; ++k) acc = fmaf(vi[k], V[j][k], acc);
            tri2[t++] = acc;
        }
    }

    #pragma unroll
    for (int c = 0; c < NCLS; ++c) {
        float acc = lin_b[c];
        #pragma unroll
        for (int k = 0; k < NTRI; ++k) acc = fmaf(tri2[k], lin_w[c * NTRI + k], acc);
        out[(size_t)m * NCLS + c] = acc;
    }
}

// ----------------------------------------------------------------- launch
extern "C" void kernel_launch(void* const* d_in, const int* in_sizes, int n_in,
                              void* d_out, int out_size, void* d_ws, size_t ws_size,
                              hipStream_t stream) {
    const float* x     = (const float*)d_in[0];
    const float* W1    = (const float*)d_in[1];
    const float* W2    = (const float*)d_in[2];
    const float* W3    = (const float*)d_in[3];
    const float* lin_w = (const float*)d_in[4];
    const float* lin_b = (const float*)d_in[5];
    float* out = (float*)d_out;
    float* y   = (float*)d_ws;     // 16384*16 floats

    k_main<<<BATCH / 4, 256, 0, stream>>>(x, W1, W2, W3, y);
    k_eig<<<BATCH / 64, 64, 0, stream>>>(y, lin_w, lin_b, out);
}